// Round 1
// baseline (367.351 us; speedup 1.0000x reference)
//
#include <hip/hip_runtime.h>

// GraphConvolution: out = input @ W_self + (adj @ input) @ W_agg
//                       = adj @ (input @ W_agg) + input @ W_self   [associativity]
// N=16384, F=128, fp32 in/out. Heavy op: adj(16384x16384 fp32, 1.07GB) @ Y(16384x128 bf16).
// Memory-bound: floor ~170us at 6.3 TB/s. bf16 MFMA w/ on-the-fly adj convert.
//
// ws layout: [0, 4MB)  Yt  = (input @ W_agg) in bf16, PRE-TILED staging format:
//                      elem idx = kt*8192 + (ch*128 + n)*8 + kin,  m = kt*64 + ch*8 + kin
//            [4MB,12MB) Z  = (input @ W_self) fp32 row-major

#define NROWS 16384
#define FDIM  128
#define NT    256          // K tiles of 64

typedef __attribute__((ext_vector_type(4))) float f32x4;
typedef __attribute__((ext_vector_type(8))) short short8;
typedef __attribute__((ext_vector_type(8))) __bf16 bf16x8;
typedef __attribute__((ext_vector_type(8))) unsigned short ushort8;

static __device__ __forceinline__ unsigned short f2bf(float f) {
  union { __bf16 b; unsigned short u; } cvt;
  cvt.b = (__bf16)f;   // RNE fptrunc
  return cvt.u;
}

// ---------------------------------------------------------------------------
// Kernel 1: Y = input @ W_agg (bf16, staged layout), Z = input @ W_self (fp32)
// 512 blocks x 256 thr, 32 rows/block. thread: col c = tid&127, row-group rg = tid>>7.
// ---------------------------------------------------------------------------
__global__ __launch_bounds__(256, 2)
void gcn_prep(const float* __restrict__ input, const float* __restrict__ weight,
              unsigned short* __restrict__ Yt, float* __restrict__ Z)
{
  __shared__ __align__(16) float in_lds[32 * FDIM];
  const int tid = threadIdx.x;
  const int m0  = blockIdx.x * 32;

  // stage 32 input rows (coalesced float4)
  const f32x4* src = (const f32x4*)(input + (size_t)m0 * FDIM);
  f32x4* dst = (f32x4*)in_lds;
#pragma unroll
  for (int i = 0; i < 4; ++i) dst[i * 256 + tid] = src[i * 256 + tid];
  __syncthreads();

  const int c  = tid & 127;
  const int rg = tid >> 7;      // rows rg*16 .. rg*16+15 (local)

  float accz[16], accy[16];
#pragma unroll
  for (int r = 0; r < 16; ++r) { accz[r] = 0.f; accy[r] = 0.f; }

  for (int k4 = 0; k4 < 32; ++k4) {
    float wsv[4], wav[4];
#pragma unroll
    for (int j = 0; j < 4; ++j) {
      wsv[j] = weight[(size_t)(k4 * 4 + j) * FDIM + c];
      wav[j] = weight[(size_t)(k4 * 4 + j + FDIM) * FDIM + c];
    }
#pragma unroll
    for (int r = 0; r < 16; ++r) {
      const f32x4 vin = *(const f32x4*)&in_lds[(rg * 16 + r) * FDIM + k4 * 4];
#pragma unroll
      for (int j = 0; j < 4; ++j) {
        accz[r] += vin[j] * wsv[j];
        accy[r] += vin[j] * wav[j];
      }
    }
  }

  // Z: row-major fp32 (coalesced across c)
#pragma unroll
  for (int r = 0; r < 16; ++r)
    Z[(size_t)(m0 + rg * 16 + r) * FDIM + c] = accz[r];

  // Yt staged: per 8-row group, thread writes 8 bf16 contiguous (16B, coalesced)
  const int kt = m0 >> 6;   // 32-row block never straddles a 64-row tile
#pragma unroll
  for (int g = 0; g < 2; ++g) {
    const int mbase = m0 + rg * 16 + g * 8;     // multiple of 8
    const int ch = (mbase >> 3) & 7;
    ushort8 v;
#pragma unroll
    for (int j = 0; j < 8; ++j) v[j] = f2bf(accy[g * 8 + j]);
    *(ushort8*)&Yt[(size_t)kt * 8192 + (size_t)(ch * 128 + c) * 8] = v;
  }
}

// ---------------------------------------------------------------------------
// Kernel 2: out = adj @ Y + Z.  BM=32 x BN=128, BK=64, 512 blocks x 256 thr.
// 4 waves: rg = wv>>1 (16-row strip), nh = wv&1 (64-col half).
// A: global->reg fp32 (wave-exclusive rows), convert bf16 in-reg.
// B: global_load_lds (linear, pre-tiled format), double-buffered, 2-phase.
// ---------------------------------------------------------------------------
__global__ __launch_bounds__(256, 2)
void gcn_main(const float* __restrict__ adj, const unsigned short* __restrict__ Yt,
              const float* __restrict__ Z, float* __restrict__ out)
{
  __shared__ unsigned short Bt[2][8192];   // [buf][(ch*128+n)*8+kin], 16KB each

  const int tid  = threadIdx.x;
  const int lane = tid & 63;
  const int wv   = tid >> 6;
  const int rg   = wv >> 1;
  const int nh   = wv & 1;
  const int m0   = blockIdx.x * 32;
  const int rlo  = lane & 15;
  const int kgrp = lane >> 4;                       // 0..3
  const size_t rowoff = (size_t)(m0 + rg * 16 + rlo) * NROWS;

  f32x4 acc[4];
#pragma unroll
  for (int f = 0; f < 4; ++f) acc[f] = (f32x4){0.f, 0.f, 0.f, 0.f};

  auto stageB = [&](int buf, int kt) {
    const unsigned short* src = Yt + (size_t)kt * 8192;
#pragma unroll
    for (int i = 0; i < 4; ++i) {
      const int chunk = wv * 4 + i;                 // 16 chunks of 1KB
      __builtin_amdgcn_global_load_lds(
          (const __attribute__((address_space(1))) void*)(src + chunk * 512 + lane * 8),
          (__attribute__((address_space(3))) void*)(&Bt[buf][chunk * 512]),
          16, 0, 0);
    }
  };
  auto loadA = [&](f32x4* a, int kt) {
    const float* p = adj + rowoff + (size_t)kt * 64 + kgrp * 8;
    a[0] = *(const f32x4*)(p);
    a[1] = *(const f32x4*)(p + 4);
    a[2] = *(const f32x4*)(p + 32);
    a[3] = *(const f32x4*)(p + 36);
  };

  f32x4 aC[4], aN[4];
  stageB(0, 0);
  loadA(aC, 0);
  __syncthreads();   // drains vmcnt(0) -> buf0 + aC ready

  for (int kt = 0; kt < NT; ++kt) {
    const int buf = kt & 1;
    if (kt < NT - 1) { stageB(buf ^ 1, kt + 1); loadA(aN, kt + 1); }

    // convert A fp32 -> bf16 frags (2 k-steps of 32)
    short8 a8[2];
#pragma unroll
    for (int s = 0; s < 2; ++s) {
      bf16x8 av;
#pragma unroll
      for (int j = 0; j < 4; ++j) {
        av[j]     = (__bf16)aC[s * 2][j];
        av[j + 4] = (__bf16)aC[s * 2 + 1][j];
      }
      a8[s] = __builtin_bit_cast(short8, av);
    }

#pragma unroll
    for (int s = 0; s < 2; ++s) {
      const int ch = s * 4 + kgrp;
#pragma unroll
      for (int f = 0; f < 4; ++f) {
        const int n = nh * 64 + f * 16 + rlo;
        const short8 b8 = *(const short8*)&Bt[buf][(size_t)(ch * 128 + n) * 8];
        acc[f] = __builtin_amdgcn_mfma_f32_16x16x32_bf16(a8[s], b8, acc[f], 0, 0, 0);
      }
    }

    __syncthreads();   // drain stage(kt+1)+loadA(kt+1), all waves done with buf
#pragma unroll
    for (int i = 0; i < 4; ++i) aC[i] = aN[i];
  }

  // epilogue: out = acc + Z.  C/D layout: row=(lane>>4)*4+reg, col=lane&15
  const int rowb = m0 + rg * 16 + (lane >> 4) * 4;
#pragma unroll
  for (int f = 0; f < 4; ++f) {
    const int col = nh * 64 + f * 16 + rlo;
#pragma unroll
    for (int r = 0; r < 4; ++r) {
      const size_t idx = (size_t)(rowb + r) * FDIM + col;
      out[idx] = acc[f][r] + Z[idx];
    }
  }
}

extern "C" void kernel_launch(void* const* d_in, const int* in_sizes, int n_in,
                              void* d_out, int out_size, void* d_ws, size_t ws_size,
                              hipStream_t stream) {
  const float* input  = (const float*)d_in[0];
  const float* adj    = (const float*)d_in[1];
  const float* weight = (const float*)d_in[2];
  float* out = (float*)d_out;

  unsigned short* Yt = (unsigned short*)d_ws;                           // 4MB bf16
  float* Z = (float*)((char*)d_ws + (size_t)NROWS * FDIM * 2);          // 8MB fp32

  gcn_prep<<<512, 256, 0, stream>>>(input, weight, Yt, Z);
  gcn_main<<<512, 256, 0, stream>>>(adj, Yt, Z, out);
}

// Round 2
// 284.643 us; speedup vs baseline: 1.2906x; 1.2906x over previous
//
#include <hip/hip_runtime.h>

// GraphConvolution: out = input @ W_self + (adj @ input) @ W_agg
//                       = adj @ (input @ W_agg) + input @ W_self   [associativity]
// Heavy op: adj(16384x16384 fp32, 1.07GB) @ Y(16384x128 bf16) -> memory-bound,
// floor ~170us @6.4TB/s. bf16 MFMA, adj converted fp32->bf16 after LDS staging.
//
// gcn_main: depth-3 pipeline, counted vmcnt(6) (T3/T4), raw s_barrier (1/iter).
// A staged via global_load_lds with inverse-swizzled source (rule 21):
// LDS slot (row, jj) holds global 16B-chunk jj ^ (row&7) -> conflict-free b128 reads.
//
// ws: [0,4MB) Yt bf16 pre-tiled: elem = kt*8192 + (ch*128+n)*8 + kin, m = kt*64+ch*8+kin
//     [4MB,12MB) Z fp32 row-major

#define NROWS 16384
#define FDIM  128
#define NT    256          // K tiles of 64
#define DEPTH 3

typedef __attribute__((ext_vector_type(4))) float f32x4;
typedef __attribute__((ext_vector_type(8))) short short8;
typedef __attribute__((ext_vector_type(8))) __bf16 bf16x8;
typedef __attribute__((ext_vector_type(8))) unsigned short ushort8;

static __device__ __forceinline__ unsigned short f2bf(float f) {
  union { __bf16 b; unsigned short u; } cvt;
  cvt.b = (__bf16)f;   // RNE fptrunc
  return cvt.u;
}

// ---------------------------------------------------------------------------
// Kernel 1: Y = input @ W_agg (bf16, staged layout), Z = input @ W_self (fp32)
// ---------------------------------------------------------------------------
__global__ __launch_bounds__(256, 2)
void gcn_prep(const float* __restrict__ input, const float* __restrict__ weight,
              unsigned short* __restrict__ Yt, float* __restrict__ Z)
{
  __shared__ __align__(16) float in_lds[32 * FDIM];
  const int tid = threadIdx.x;
  const int m0  = blockIdx.x * 32;

  const f32x4* src = (const f32x4*)(input + (size_t)m0 * FDIM);
  f32x4* dst = (f32x4*)in_lds;
#pragma unroll
  for (int i = 0; i < 4; ++i) dst[i * 256 + tid] = src[i * 256 + tid];
  __syncthreads();

  const int c  = tid & 127;
  const int rg = tid >> 7;

  float accz[16], accy[16];
#pragma unroll
  for (int r = 0; r < 16; ++r) { accz[r] = 0.f; accy[r] = 0.f; }

  for (int k4 = 0; k4 < 32; ++k4) {
    float wsv[4], wav[4];
#pragma unroll
    for (int j = 0; j < 4; ++j) {
      wsv[j] = weight[(size_t)(k4 * 4 + j) * FDIM + c];
      wav[j] = weight[(size_t)(k4 * 4 + j + FDIM) * FDIM + c];
    }
#pragma unroll
    for (int r = 0; r < 16; ++r) {
      const f32x4 vin = *(const f32x4*)&in_lds[(rg * 16 + r) * FDIM + k4 * 4];
#pragma unroll
      for (int j = 0; j < 4; ++j) {
        accz[r] += vin[j] * wsv[j];
        accy[r] += vin[j] * wav[j];
      }
    }
  }

#pragma unroll
  for (int r = 0; r < 16; ++r)
    Z[(size_t)(m0 + rg * 16 + r) * FDIM + c] = accz[r];

  const int kt = m0 >> 6;
#pragma unroll
  for (int g = 0; g < 2; ++g) {
    const int mbase = m0 + rg * 16 + g * 8;
    const int ch = (mbase >> 3) & 7;
    ushort8 v;
#pragma unroll
    for (int j = 0; j < 8; ++j) v[j] = f2bf(accy[g * 8 + j]);
    *(ushort8*)&Yt[(size_t)kt * 8192 + (size_t)(ch * 128 + c) * 8] = v;
  }
}

// ---------------------------------------------------------------------------
// Kernel 2: out = adj @ Y + Z.  BM=32 BN=128 BK=64. 512 blocks x 256 thr.
// depth-3 LDS rotation, 6 vm-ops/wave/tile, vmcnt(6), one raw barrier/iter.
// ---------------------------------------------------------------------------
__global__ __launch_bounds__(256, 2)
void gcn_main(const float* __restrict__ adj, const unsigned short* __restrict__ Yt,
              const float* __restrict__ Z, float* __restrict__ out)
{
  // per buffer: [0,16384) B bf16 tiled, [16384,24576) A fp32 row-major swizzled
  __shared__ __align__(16) unsigned char lds[DEPTH][24576];

  const int tid  = threadIdx.x;
  const int lane = tid & 63;
  const int wv   = tid >> 6;
  const int rg   = wv >> 1;      // 16-row strip
  const int nh   = wv & 1;       // 64-col half
  const int m0   = blockIdx.x * 32;
  const int rlo  = lane & 15;
  const int kgrp = lane >> 4;

  f32x4 acc[4];
#pragma unroll
  for (int f = 0; f < 4; ++f) acc[f] = (f32x4){0.f, 0.f, 0.f, 0.f};

  auto stage = [&](int buf, int kt) {
    // B tile: 16KB, 4 issues/wave, linear (pre-tiled in Yt)
    const unsigned short* bs = Yt + (size_t)kt * 8192;
#pragma unroll
    for (int i = 0; i < 4; ++i) {
      const int chunk = wv * 4 + i;
      __builtin_amdgcn_global_load_lds(
          (const __attribute__((address_space(1))) void*)(bs + chunk * 512 + lane * 8),
          (__attribute__((address_space(3))) void*)(&lds[buf][chunk * 1024]),
          16, 0, 0);
    }
    // A tile: 32 rows x 256B = 8KB, 2 issues/wave. LDS dest linear (slot t),
    // global source chunk = (t&15) ^ (row&7)  [inverse swizzle]
#pragma unroll
    for (int i = 0; i < 2; ++i) {
      const int row = i * 16 + (tid >> 4);
      const int j   = (tid & 15) ^ ((tid >> 4) & 7);
      const float* as = adj + (size_t)(m0 + row) * NROWS + (size_t)kt * 64 + j * 4;
      __builtin_amdgcn_global_load_lds(
          (const __attribute__((address_space(1))) void*)as,
          (__attribute__((address_space(3))) void*)(&lds[buf][16384 + i * 4096 + wv * 1024]),
          16, 0, 0);
    }
  };

  // prologue: tiles 0 and 1 in flight (12 vm-ops/wave)
  stage(0, 0);
  stage(1, 1);

  const int arow = (rg * 16 + rlo) * 256;   // byte offset of this lane's A row
  const int aswz = rlo & 7;

  int bc = 0;   // kt % 3 (compute buffer)
  int bn = 2;   // (kt+2) % 3 (stage target)

  for (int kt = 0; kt < NT; ++kt) {
    if (kt < NT - 1) {
      asm volatile("s_waitcnt vmcnt(6)" ::: "memory");   // tile kt staged; kt+1 in flight
    } else {
      asm volatile("s_waitcnt vmcnt(0)" ::: "memory");   // last tile: drain
    }
    __builtin_amdgcn_s_barrier();
    __builtin_amdgcn_sched_barrier(0);

    if (kt + 2 < NT) stage(bn, kt + 2);   // overwrites buf freed by barrier

    const unsigned char* Bp = lds[bc];
    const unsigned char* Ap = Bp + 16384;

    // A frags: k = s*32 + kgrp*8 + {0..7}  -> chunks c0 = s*8+kgrp*2, c0+1 (swizzled)
    short8 a8[2];
#pragma unroll
    for (int s = 0; s < 2; ++s) {
      const int c0 = s * 8 + kgrp * 2;
      const f32x4 lo = *(const f32x4*)(Ap + arow + ((c0    ) ^ aswz) * 16);
      const f32x4 hi = *(const f32x4*)(Ap + arow + ((c0 + 1) ^ aswz) * 16);
      bf16x8 av;
#pragma unroll
      for (int j = 0; j < 4; ++j) {
        av[j]     = (__bf16)lo[j];
        av[j + 4] = (__bf16)hi[j];
      }
      a8[s] = __builtin_bit_cast(short8, av);
    }

#pragma unroll
    for (int s = 0; s < 2; ++s) {
      const int ch = s * 4 + kgrp;
#pragma unroll
      for (int f = 0; f < 4; ++f) {
        const int n = nh * 64 + f * 16 + rlo;
        const short8 b8 = *(const short8*)(Bp + (size_t)(ch * 128 + n) * 16);
        acc[f] = __builtin_amdgcn_mfma_f32_16x16x32_bf16(a8[s], b8, acc[f], 0, 0, 0);
      }
    }

    bc = (bc == DEPTH - 1) ? 0 : bc + 1;
    bn = (bn == DEPTH - 1) ? 0 : bn + 1;
  }

  // epilogue: out = acc + Z.  C/D: row=(lane>>4)*4+reg, col=lane&15
  const int rowb = m0 + rg * 16 + (lane >> 4) * 4;
#pragma unroll
  for (int f = 0; f < 4; ++f) {
    const int col = nh * 64 + f * 16 + rlo;
#pragma unroll
    for (int r = 0; r < 4; ++r) {
      const size_t idx = (size_t)(rowb + r) * FDIM + col;
      out[idx] = acc[f][r] + Z[idx];
    }
  }
}

extern "C" void kernel_launch(void* const* d_in, const int* in_sizes, int n_in,
                              void* d_out, int out_size, void* d_ws, size_t ws_size,
                              hipStream_t stream) {
  const float* input  = (const float*)d_in[0];
  const float* adj    = (const float*)d_in[1];
  const float* weight = (const float*)d_in[2];
  float* out = (float*)d_out;

  unsigned short* Yt = (unsigned short*)d_ws;                           // 4MB bf16
  float* Z = (float*)((char*)d_ws + (size_t)NROWS * FDIM * 2);          // 8MB fp32

  gcn_prep<<<512, 256, 0, stream>>>(input, weight, Yt, Z);
  gcn_main<<<512, 256, 0, stream>>>(adj, Yt, Z, out);
}

// Round 3
// 206.904 us; speedup vs baseline: 1.7755x; 1.3757x over previous
//
#include <hip/hip_runtime.h>

// GraphConvolution: out = input @ W_self + (adj @ input) @ W_agg
//                       = adj @ (input @ W_agg) + input @ W_self   [associativity]
// Heavy op: adj(16384x16384 fp32, 1.07GB) @ Y(16384x128 bf16) -> memory-bound,
// floor ~168us @6.4TB/s.
//
// gcn_main r3: BM=64 BK=128, 512thr (8 waves: 4M x 2N), grid 256 (1 blk/CU).
//  - depth-2 LDS pipeline, counted vmcnt(8) (T3/T4), stage-at-bottom, 2 barriers/iter
//  - adj staged with NT cache policy (aux=2): one-shot stream, don't thrash L2
//    so Yt (4MB, re-read by all blocks) stays L2-resident
//  - A via global_load_lds, rule-21 both-sides XOR swizzle (chunk ^= row&7)
//  - B (Yt) pre-tiled by gcn_prep for linear global_load_lds + conflict-free b128
//
// ws: [0,4MB) Yt bf16 pre-tiled: elem = kt*16384 + (ch*128+n)*8 + kin,
//     where kt=m>>7, ch=(m>>3)&15, kin=m&7.   [4MB,12MB) Z fp32 row-major.

#define NROWS 16384
#define FDIM  128
#define NT2   128          // K tiles of 128

typedef __attribute__((ext_vector_type(4))) float f32x4;
typedef __attribute__((ext_vector_type(8))) short short8;
typedef __attribute__((ext_vector_type(8))) __bf16 bf16x8;
typedef __attribute__((ext_vector_type(8))) unsigned short ushort8;

static __device__ __forceinline__ unsigned short f2bf(float f) {
  union { __bf16 b; unsigned short u; } cvt;
  cvt.b = (__bf16)f;   // RNE fptrunc
  return cvt.u;
}

// ---------------------------------------------------------------------------
// Kernel 1: Y = input @ W_agg (bf16, pre-tiled), Z = input @ W_self (fp32)
// ---------------------------------------------------------------------------
__global__ __launch_bounds__(256, 2)
void gcn_prep(const float* __restrict__ input, const float* __restrict__ weight,
              unsigned short* __restrict__ Yt, float* __restrict__ Z)
{
  __shared__ __align__(16) float in_lds[32 * FDIM];
  const int tid = threadIdx.x;
  const int m0  = blockIdx.x * 32;

  const f32x4* src = (const f32x4*)(input + (size_t)m0 * FDIM);
  f32x4* dst = (f32x4*)in_lds;
#pragma unroll
  for (int i = 0; i < 4; ++i) dst[i * 256 + tid] = src[i * 256 + tid];
  __syncthreads();

  const int c  = tid & 127;
  const int rg = tid >> 7;

  float accz[16], accy[16];
#pragma unroll
  for (int r = 0; r < 16; ++r) { accz[r] = 0.f; accy[r] = 0.f; }

  for (int k4 = 0; k4 < 32; ++k4) {
    float wsv[4], wav[4];
#pragma unroll
    for (int j = 0; j < 4; ++j) {
      wsv[j] = weight[(size_t)(k4 * 4 + j) * FDIM + c];
      wav[j] = weight[(size_t)(k4 * 4 + j + FDIM) * FDIM + c];
    }
#pragma unroll
    for (int r = 0; r < 16; ++r) {
      const f32x4 vin = *(const f32x4*)&in_lds[(rg * 16 + r) * FDIM + k4 * 4];
#pragma unroll
      for (int j = 0; j < 4; ++j) {
        accz[r] += vin[j] * wsv[j];
        accy[r] += vin[j] * wav[j];
      }
    }
  }

#pragma unroll
  for (int r = 0; r < 16; ++r)
    Z[(size_t)(m0 + rg * 16 + r) * FDIM + c] = accz[r];

  const int kt = m0 >> 7;   // 32-row block never straddles a 128-row tile
#pragma unroll
  for (int g = 0; g < 2; ++g) {
    const int mbase = m0 + rg * 16 + g * 8;
    const int ch = (mbase >> 3) & 15;
    ushort8 v;
#pragma unroll
    for (int j = 0; j < 8; ++j) v[j] = f2bf(accy[g * 8 + j]);
    *(ushort8*)&Yt[(size_t)kt * 16384 + (size_t)(ch * 128 + c) * 8] = v;
  }
}

// ---------------------------------------------------------------------------
// Kernel 2: out = adj @ Y + Z.  BM=64 BN=128 BK=128. 256 blocks x 512 thr.
// ---------------------------------------------------------------------------
__global__ __launch_bounds__(512, 1)
void gcn_main(const float* __restrict__ adj, const unsigned short* __restrict__ Yt,
              const float* __restrict__ Z, float* __restrict__ out)
{
  // per buffer: [0,32768) B bf16 tiled, [32768,65536) A fp32 swizzled (64 rows x 512B)
  __shared__ __align__(16) unsigned char lds[2][65536];

  const int tid  = threadIdx.x;
  const int lane = tid & 63;
  const int wv   = tid >> 6;     // 0..7
  const int rg   = wv >> 1;      // 16-row strip (0..3)
  const int nh   = wv & 1;       // 64-col half
  const int m0   = blockIdx.x * 64;
  const int rlo  = lane & 15;
  const int kgrp = lane >> 4;    // 0..3

  f32x4 acc[4];
#pragma unroll
  for (int f = 0; f < 4; ++f) acc[f] = (f32x4){0.f, 0.f, 0.f, 0.f};

  auto stage = [&](int buf, int kt) {
    // B tile: 32KB, 4 issues/wave, linear (pre-tiled in Yt), cached (L2-resident)
    const unsigned short* bs = Yt + (size_t)kt * 16384;
#pragma unroll
    for (int i = 0; i < 4; ++i) {
      const int q = wv * 4 + i;                     // 32 chunks of 1KB
      __builtin_amdgcn_global_load_lds(
          (const __attribute__((address_space(1))) void*)(bs + q * 512 + lane * 8),
          (__attribute__((address_space(3))) void*)(&lds[buf][q * 1024]),
          16, 0, 0);
    }
    // A tile: 64 rows x 512B = 32KB, 4 issues/wave (1KB = 2 rows each).
    // LDS dest linear; global source chunk = t ^ (row&7)  [inverse swizzle], NT policy.
#pragma unroll
    for (int i = 0; i < 4; ++i) {
      const int p     = wv * 4 + i;                 // row pair
      const int row_g = 2 * p + (lane >> 5);
      const int j     = (lane & 31) ^ (row_g & 7);
      const float* as = adj + (size_t)(m0 + row_g) * NROWS + (size_t)kt * 128 + j * 4;
      __builtin_amdgcn_global_load_lds(
          (const __attribute__((address_space(1))) void*)as,
          (__attribute__((address_space(3))) void*)(&lds[buf][32768 + p * 1024]),
          16, 0, 2 /* NT: non-temporal, don't evict Yt from L2 */);
    }
  };

  // prologue: tiles 0,1 in flight (16 ops/wave)
  stage(0, 0);
  stage(1, 1);

  const int arow = (rg * 16 + rlo) * 512;   // byte offset of this lane's A row
  const int aswz = rlo & 7;

  for (int kt = 0; kt < NT2; ++kt) {
    if (kt < NT2 - 1) {
      asm volatile("s_waitcnt vmcnt(8)" ::: "memory");   // stage(kt) landed; kt+1 in flight
    } else {
      asm volatile("s_waitcnt vmcnt(0)" ::: "memory");
    }
    __builtin_amdgcn_sched_barrier(0);
    __builtin_amdgcn_s_barrier();                       // buf[kt&1] fully staged, all waves
    __builtin_amdgcn_sched_barrier(0);

    const int buf = kt & 1;
    const unsigned char* Bp = lds[buf];
    const unsigned char* Ap = Bp + 32768;

    // A frags: k-step s (K=32): k = s*32 + kgrp*8 + {0..7} -> chunks s*8+kgrp*2, +1
    short8 a8[4];
#pragma unroll
    for (int s = 0; s < 4; ++s) {
      const int c0 = s * 8 + kgrp * 2;
      const f32x4 lo = *(const f32x4*)(Ap + arow + ((c0    ) ^ aswz) * 16);
      const f32x4 hi = *(const f32x4*)(Ap + arow + ((c0 + 1) ^ aswz) * 16);
      bf16x8 av;
#pragma unroll
      for (int j = 0; j < 4; ++j) {
        av[j]     = (__bf16)lo[j];
        av[j + 4] = (__bf16)hi[j];
      }
      a8[s] = __builtin_bit_cast(short8, av);
    }

#pragma unroll
    for (int s = 0; s < 4; ++s) {
      const int ch = s * 4 + kgrp;
#pragma unroll
      for (int f = 0; f < 4; ++f) {
        const int n = nh * 64 + f * 16 + rlo;
        const short8 b8 = *(const short8*)(Bp + (size_t)(ch * 128 + n) * 16);
        acc[f] = __builtin_amdgcn_mfma_f32_16x16x32_bf16(a8[s], b8, acc[f], 0, 0, 0);
      }
    }

    __builtin_amdgcn_s_barrier();                       // all waves done reading buf
    __builtin_amdgcn_sched_barrier(0);
    if (kt + 2 < NT2) stage(buf, kt + 2);               // overwrite freed buf
  }

  // epilogue: out = acc + Z.  C/D: row=(lane>>4)*4+reg, col=lane&15
  const int rowb = m0 + rg * 16 + (lane >> 4) * 4;
#pragma unroll
  for (int f = 0; f < 4; ++f) {
    const int col = nh * 64 + f * 16 + rlo;
#pragma unroll
    for (int r = 0; r < 4; ++r) {
      const size_t idx = (size_t)(rowb + r) * FDIM + col;
      out[idx] = acc[f][r] + Z[idx];
    }
  }
}

extern "C" void kernel_launch(void* const* d_in, const int* in_sizes, int n_in,
                              void* d_out, int out_size, void* d_ws, size_t ws_size,
                              hipStream_t stream) {
  const float* input  = (const float*)d_in[0];
  const float* adj    = (const float*)d_in[1];
  const float* weight = (const float*)d_in[2];
  float* out = (float*)d_out;

  unsigned short* Yt = (unsigned short*)d_ws;                           // 4MB bf16
  float* Z = (float*)((char*)d_ws + (size_t)NROWS * FDIM * 2);          // 8MB fp32

  gcn_prep<<<512, 256, 0, stream>>>(input, weight, Yt, Z);
  gcn_main<<<256, 512, 0, stream>>>(adj, Yt, Z, out);
}